// Round 11
// baseline (64.511 us; speedup 1.0000x reference)
//
#include <hip/hip_runtime.h>
#include <hip/hip_bf16.h>

// Conv2d: B=16, CIN=128, COUT=256, H=W=56, 3x3, stride1, pad1, fp32, + bias.
// Implicit GEMM, bf16 MFMA. M=256(co), N=16*56*64=57344(px, W padded 64), K=1152.
// R11: 128x128 block, 4 waves of 64x64 (acc=64 regs -> 3 waves/SIMD -> 3 blocks/CU),
// BK=32, dbuf 2x16KB, 32x32x16 MFMA (2495 TF ceiling, half the issue slots),
// R10-proven 4-slot XOR swizzle slot=kg^((row>>1)&3) (0 conflicts), R3-style loop
// (stage-early + one __syncthreads). Vectorized prep (ci-paired transpose).

#define XT_BYTES   15204352u   // 16*58*64*128*2
#define SLACK      8192u
#define WT_OFFSET  (XT_BYTES + SLACK)
#define WT_BYTES   589824u     // 36 kt * 2 pm * 8KB
#define WS_NEED    (WT_OFFSET + WT_BYTES)

typedef __bf16 bf16x8 __attribute__((ext_vector_type(8)));
typedef float  f32x4  __attribute__((ext_vector_type(4)));
typedef float  f32x16 __attribute__((ext_vector_type(16)));
typedef unsigned short ushort8v __attribute__((ext_vector_type(8)));

__device__ __forceinline__ unsigned short f2bf(float f) {
  unsigned u = __builtin_bit_cast(unsigned, f);
  u += 0x7fffu + ((u >> 16) & 1u);
  return (unsigned short)(u >> 16);
}

__device__ __forceinline__ void gll16(const void* g, const void* l) {
  __builtin_amdgcn_global_load_lds(
      (const __attribute__((address_space(1))) unsigned int*)g,
      (__attribute__((address_space(3))) unsigned int*)l, 16, 0, 0);
}

// ---------------- fused prep kernel ----------------
// blocks 0..447: xtrans for (b, h-pair) — vectorized both sides + col pads
// blocks 448..479: zero rows 0 / 57 per image
// blocks 480..497: wtrans (2 K-tiles each) -> wt[kt][pm][512 slots x 16B] pre-swizzled
__global__ void prep(const float* __restrict__ x, const float* __restrict__ wsrc,
                     unsigned short* __restrict__ xt, unsigned short* __restrict__ wt) {
  int blk = blockIdx.x;
  int t = threadIdx.x;   // 256
  if (blk < 448) {
    __shared__ unsigned short tile[2][58][136];   // +8 ushort pad (16B) per row
    int b = blk / 28, hp = blk % 28;
    // phase 1: load 2 ci rows x 28 w, write ushort2 (ci-pair) per w
    int ci2 = t & 63, half = (t >> 6) & 1, hh = t >> 7;
    int h = hp * 2 + hh;
    const float* s0 = x + ((size_t)(b * 128 + ci2 * 2)) * 3136 + h * 56 + half * 28;
    const float* s1 = s0 + 3136;
    #pragma unroll
    for (int q = 0; q < 7; ++q) {
      float4 v0 = *(const float4*)&s0[q * 4];
      float4 v1 = *(const float4*)&s1[q * 4];
      int w = 1 + half * 28 + q * 4;
      unsigned short* dst = &tile[hh][0][0] + (size_t)w * 136 + ci2 * 2;
      *(unsigned*)(dst)       = (unsigned)f2bf(v0.x) | ((unsigned)f2bf(v1.x) << 16);
      *(unsigned*)(dst + 136) = (unsigned)f2bf(v0.y) | ((unsigned)f2bf(v1.y) << 16);
      *(unsigned*)(dst + 272) = (unsigned)f2bf(v0.z) | ((unsigned)f2bf(v1.z) << 16);
      *(unsigned*)(dst + 408) = (unsigned)f2bf(v0.w) | ((unsigned)f2bf(v1.w) << 16);
    }
    __syncthreads();
    // phase 2: write xt rows (vectorized b128 reads, coalesced 128B stores)
    int s = t & 127, hh2 = t >> 7;
    int w = s >> 1, part = s & 1;
    unsigned short* dst = xt + (size_t)b * 475136 +
                          (size_t)(hp * 2 + hh2 + 1) * 8192 + w * 128 + part * 64;
    if (w == 0 || w >= 57) {
      uint4 z; z.x = z.y = z.z = z.w = 0u;
      #pragma unroll
      for (int i = 0; i < 8; ++i) *(uint4*)(dst + i * 8) = z;
    } else {
      const unsigned short* srcl = &tile[hh2][0][0] + (size_t)w * 136 + part * 64;
      #pragma unroll
      for (int i = 0; i < 8; ++i)
        *(uint4*)(dst + i * 8) = *(const uint4*)(srcl + i * 8);
    }
  } else if (blk < 480) {
    int idx = blk - 448;
    int b = idx >> 1, zr = (idx & 1) ? 57 : 0;
    uint4* dst = (uint4*)(xt + (size_t)b * 475136 + (size_t)zr * 8192);
    uint4 z; z.x = z.y = z.z = z.w = 0u;
    #pragma unroll
    for (int q = 0; q < 4; ++q) dst[t + q * 256] = z;
  } else {
    int kidx = blk - 480;            // 0..17
    #pragma unroll
    for (int kk = 0; kk < 2; ++kk) {
      int kt = kidx * 2 + kk;        // 0..35
      int tap = kt >> 2, ci0 = (kt & 3) * 32;
      #pragma unroll
      for (int pm = 0; pm < 2; ++pm) {
        #pragma unroll
        for (int q = 0; q < 2; ++q) {
          int n = t + q * 256;       // 0..511
          int r = n >> 2, sslot = n & 3;
          int kg = sslot ^ ((r >> 1) & 3);
          int co = pm * 128 + r;
          const float* src = wsrc + (size_t)co * 1152 + (size_t)(ci0 + kg * 8) * 9 + tap;
          ushort8v v;
          #pragma unroll
          for (int j = 0; j < 8; ++j) v[j] = f2bf(src[j * 9]);
          *(ushort8v*)&wt[((size_t)kt * 1024 + pm * 512 + n) * 8] = v;
        }
      }
    }
  }
}

// ---------------- main GEMM kernel ----------------
// LDS buffer (16KB): A [128co][32k] @0 (64B rows), B [128px][32k] @8192.
// Row r, pos p holds k-group kg = p ^ ((r>>1)&3)  (R10-proven 0-conflict).

__global__ __launch_bounds__(256, 3) void conv_gemm(
    const unsigned short* __restrict__ xt,
    const char* __restrict__ wt,
    const float* __restrict__ bias,
    float* __restrict__ out) {
  __shared__ __align__(16) char lds[32768];    // 2 x 16KB

  int bid = blockIdx.x;
  int sw = (bid & 7) * 112 + (bid >> 3);       // XCD swizzle, 896 = 8*112
  int pm = sw & 1;                             // co half
  int pn = sw >> 1;                            // 0..447 pixel tile
  int bimg = pn / 28;
  int h0 = (pn - bimg * 28) * 2;               // 2 output rows (64px each)

  int tid = threadIdx.x;
  int wv = tid >> 6, l = tid & 63;
  int wm = wv >> 1, wn = wv & 1;               // 2M x 2N waves, 64x64 each
  int l31 = l & 31, lg2 = l >> 5;
  int rx = (l >> 1) & 3;                       // (row>>1)&3 within 32-row frag

  // fragment read byte offsets: a[mb][k16], b[nb][k16]
  int aRd[2][2], bRd[2][2];
  #pragma unroll
  for (int mb = 0; mb < 2; ++mb)
    #pragma unroll
    for (int k16 = 0; k16 < 2; ++k16) {
      int row = wm * 64 + mb * 32 + l31;
      aRd[mb][k16] = row * 64 + (((k16 * 2 + lg2) ^ rx) << 4);
      int prow = wn * 64 + mb * 32 + l31;
      bRd[mb][k16] = 8192 + prow * 64 + (((k16 * 2 + lg2) ^ rx) << 4);
    }

  // staging sources (LDS dest linear; inverse swizzle folded into source)
  const char* aS = wt + pm * 8192 + tid * 16;  // + kt*16384, second at +4096
  const unsigned short* bS[2];
  #pragma unroll
  for (int j = 0; j < 2; ++j) {
    int n = tid + j * 256;                     // 0..511
    int px = n >> 2, p = n & 3;
    int kg = p ^ ((px >> 1) & 3);
    bS[j] = xt + ((size_t)((bimg * 58 + h0 + (px >> 6)) * 64 + (px & 63))) * 128 + kg * 8;
  }

  f32x16 acc[2][2];
  #pragma unroll
  for (int mb = 0; mb < 2; ++mb)
    #pragma unroll
    for (int nb = 0; nb < 2; ++nb)
      #pragma unroll
      for (int e = 0; e < 16; ++e) acc[mb][nb][e] = 0.f;

  auto stage = [&](int kt, int buf) {
    int tap = kt >> 2;
    int kh = tap >= 6 ? 2 : (tap >= 3 ? 1 : 0);
    int kw = tap - kh * 3;
    int koff = (kh * 64 + kw) * 128 + (kt & 3) * 32;   // ushort units
    const char* sA = aS + kt * 16384;
    char* dA = &lds[buf * 16384 + tid * 16];
    char* dB = &lds[buf * 16384 + 8192 + tid * 16];
    gll16(sA, dA);
    gll16(sA + 4096, dA + 4096);
    gll16(bS[0] + koff, dB);
    gll16(bS[1] + koff, dB + 4096);
  };

  stage(0, 0);
  __syncthreads();

  for (int kt = 0; kt < 36; ++kt) {
    const char* base = &lds[(kt & 1) * 16384];
    if (kt < 35) stage(kt + 1, (kt + 1) & 1);   // prefetch into other buffer
    bf16x8 a[2][2], b[2][2];
    #pragma unroll
    for (int mb = 0; mb < 2; ++mb)
      #pragma unroll
      for (int k16 = 0; k16 < 2; ++k16) {
        a[mb][k16] = *(const bf16x8*)(base + aRd[mb][k16]);
        b[mb][k16] = *(const bf16x8*)(base + bRd[mb][k16]);
      }
    #pragma unroll
    for (int mb = 0; mb < 2; ++mb)
      #pragma unroll
      for (int nb = 0; nb < 2; ++nb) {
        acc[mb][nb] = __builtin_amdgcn_mfma_f32_32x32x16_bf16(a[mb][0], b[nb][0], acc[mb][nb], 0, 0, 0);
        acc[mb][nb] = __builtin_amdgcn_mfma_f32_32x32x16_bf16(a[mb][1], b[nb][1], acc[mb][nb], 0, 0, 0);
      }
    if (kt < 35) __syncthreads();
  }

  // epilogue: bias + masked store. C/D 32x32: col=lane&31, row=(r&3)+8*(r>>2)+4*lg2
  #pragma unroll
  for (int mb = 0; mb < 2; ++mb)
    #pragma unroll
    for (int nb = 0; nb < 2; ++nb) {
      int px = wn * 64 + nb * 32 + l31;
      int w_ = px & 63;
      int h_ = h0 + (px >> 6);
      if (w_ < 56) {
        #pragma unroll
        for (int q = 0; q < 4; ++q) {
          int co0 = pm * 128 + wm * 64 + mb * 32 + q * 8 + lg2 * 4;
          f32x4 bb = *(const f32x4*)&bias[co0];
          float* o = out + ((size_t)(bimg * 256 + co0)) * 3136 + (size_t)h_ * 56 + w_;
          #pragma unroll
          for (int j = 0; j < 4; ++j)
            o[(size_t)j * 3136] = acc[mb][nb][q * 4 + j] + bb[j];
        }
      }
    }
}

// ---------------- fallback (tiny ws) ----------------

__global__ void conv_naive(const float* __restrict__ x, const float* __restrict__ w,
                           const float* __restrict__ bias, float* __restrict__ out) {
  int idx = blockIdx.x * 256 + threadIdx.x;
  if (idx >= 16 * 256 * 56 * 56) return;
  int wo = idx % 56; int t = idx / 56;
  int ho = t % 56; t /= 56;
  int co = t % 256; int b = t / 256;
  float acc = bias[co];
  for (int ci = 0; ci < 128; ++ci) {
    const float* xp = x + ((size_t)(b * 128 + ci)) * 3136;
    const float* wp = w + ((size_t)(co * 128 + ci)) * 9;
    for (int kh = 0; kh < 3; ++kh) {
      int hi = ho + kh - 1;
      if (hi < 0 || hi >= 56) continue;
      for (int kw = 0; kw < 3; ++kw) {
        int wi = wo + kw - 1;
        if (wi < 0 || wi >= 56) continue;
        acc += xp[hi * 56 + wi] * wp[kh * 3 + kw];
      }
    }
  }
  out[idx] = acc;
}

extern "C" void kernel_launch(void* const* d_in, const int* in_sizes, int n_in,
                              void* d_out, int out_size, void* d_ws, size_t ws_size,
                              hipStream_t stream) {
  const float* x    = (const float*)d_in[0];
  const float* wgt  = (const float*)d_in[1];
  const float* bias = (const float*)d_in[2];
  float* out = (float*)d_out;

  if (ws_size < (size_t)WS_NEED) {
    conv_naive<<<(16 * 256 * 56 * 56 + 255) / 256, 256, 0, stream>>>(x, wgt, bias, out);
    return;
  }

  unsigned short* xt = (unsigned short*)d_ws;
  unsigned short* wt = (unsigned short*)((char*)d_ws + WT_OFFSET);

  prep<<<498, 256, 0, stream>>>(x, wgt, xt, wt);
  conv_gemm<<<896, 256, 0, stream>>>(xt, (const char*)wt, bias, out);
}